// Round 1
// baseline (190.724 us; speedup 1.0000x reference)
//
#include <hip/hip_runtime.h>

// Problem constants (from reference): waveforms [N=1024, T=2000, C=64] f32,
// mask_length = int(T * 0.1) = 200.
constexpr unsigned N = 1024;
constexpr unsigned T = 2000;
constexpr unsigned C = 64;
constexpr unsigned MASK_LEN = 200;
constexpr unsigned TC = T * C;              // 128000 floats per sample
constexpr unsigned TOTAL_F4 = N * TC / 4;   // 32,768,000 float4 elements

__global__ __launch_bounds__(256) void MaskEncoding_39307540693367_kernel(
    const float4* __restrict__ in,
    const int* __restrict__ apply_mask,
    const int* __restrict__ rm,
    float4* __restrict__ out) {
    unsigned idx = blockIdx.x * blockDim.x + threadIdx.x;
    const unsigned stride = gridDim.x * blockDim.x;
    for (; idx < TOTAL_F4; idx += stride) {
        unsigned e = idx << 2;              // float element index (< 2^27, fits 32-bit)
        unsigned n = e / TC;                // magic-mul division by 128000
        unsigned rem = e - n * TC;
        unsigned t = rem >> 6;              // C = 64
        int r = rm[n];                      // 4 KB array — L1/L2 resident
        bool zero = (apply_mask[n] > 0) & ((int)t >= r) & ((int)t < r + (int)MASK_LEN);
        float4 v = make_float4(0.f, 0.f, 0.f, 0.f);
        if (!zero) v = in[idx];             // skip HBM read on masked rows (wave-uniform spans)
        out[idx] = v;
    }
}

extern "C" void kernel_launch(void* const* d_in, const int* in_sizes, int n_in,
                              void* d_out, int out_size, void* d_ws, size_t ws_size,
                              hipStream_t stream) {
    const float4* in = (const float4*)d_in[0];
    const int* apply_mask = (const int*)d_in[1];
    const int* rm = (const int*)d_in[2];
    float4* out = (float4*)d_out;

    const int block = 256;
    // 2048 blocks = 256 CUs x 8 blocks; grid-stride covers the rest.
    const int grid = 2048;
    MaskEncoding_39307540693367_kernel<<<grid, block, 0, stream>>>(in, apply_mask, rm, out);
}

// Round 2
// 171.146 us; speedup vs baseline: 1.1144x; 1.1144x over previous
//
#include <hip/hip_runtime.h>

// waveforms [N=1024, T=2000, C=64] f32; zero t-slice [rm, rm+200) when apply_mask.
// Layout: 32000 float4 per sample = 25 blocks x (256 threads x 5 float4).
// n is block-uniform -> rm/apply_mask become scalar loads, mask branch is
// wave-uniform. 16 float4 per t-step (C=64 floats).

typedef float f4 __attribute__((ext_vector_type(4)));

constexpr unsigned N = 1024;
constexpr unsigned MASK_LEN = 200;
constexpr unsigned F4_PER_SAMPLE = 32000;   // T*C/4
constexpr unsigned BLOCKS_PER_SAMPLE = 25;
constexpr unsigned F4_PER_BLOCK = 1280;     // 5 * 256
constexpr unsigned T_PER_BLOCK = 80;        // 1280 / 16
constexpr unsigned ITERS = 5;

__global__ __launch_bounds__(256) void MaskEncoding_39307540693367_kernel(
    const f4* __restrict__ in,
    const int* __restrict__ apply_mask,
    const int* __restrict__ rm,
    f4* __restrict__ out) {
    const unsigned b = blockIdx.x;
    const unsigned n = b / BLOCKS_PER_SAMPLE;            // scalar magic-div
    const unsigned c = b - n * BLOCKS_PER_SAMPLE;
    const unsigned base = n * F4_PER_SAMPLE + c * F4_PER_BLOCK;

    const int r  = rm[n];                                 // block-uniform -> s_load
    const int am = apply_mask[n];
    const int t_lo = (int)(c * T_PER_BLOCK);
    const int t_hi = t_lo + (int)T_PER_BLOCK - 1;
    const int m_lo = r;
    const int m_hi = r + (int)MASK_LEN - 1;

    const bool any_mask  = (am > 0) & (t_hi >= m_lo) & (t_lo <= m_hi);
    const bool full_mask = (am > 0) & (t_lo >= m_lo) & (t_hi <= m_hi);

    const unsigned idx0 = base + threadIdx.x;

    if (full_mask) {
        // whole chunk masked: no reads at all
        f4 z = (f4)0.f;
#pragma unroll
        for (unsigned j = 0; j < ITERS; ++j)
            __builtin_nontemporal_store(z, &out[idx0 + j * 256]);
    } else if (!any_mask) {
        // straight streaming copy: loads issue with no mask dependency
        f4 v[ITERS];
#pragma unroll
        for (unsigned j = 0; j < ITERS; ++j)
            v[j] = __builtin_nontemporal_load(&in[idx0 + j * 256]);
#pragma unroll
        for (unsigned j = 0; j < ITERS; ++j)
            __builtin_nontemporal_store(v[j], &out[idx0 + j * 256]);
    } else {
        // boundary chunk (<=2 per masked sample): per-lane select
#pragma unroll
        for (unsigned j = 0; j < ITERS; ++j) {
            const unsigned idx = idx0 + j * 256;
            const int t = (int)((idx - n * F4_PER_SAMPLE) >> 4);  // 16 f4 per t
            f4 v = __builtin_nontemporal_load(&in[idx]);
            if ((t >= m_lo) & (t <= m_hi)) v = (f4)0.f;
            __builtin_nontemporal_store(v, &out[idx]);
        }
    }
}

extern "C" void kernel_launch(void* const* d_in, const int* in_sizes, int n_in,
                              void* d_out, int out_size, void* d_ws, size_t ws_size,
                              hipStream_t stream) {
    const f4* in = (const f4*)d_in[0];
    const int* apply_mask = (const int*)d_in[1];
    const int* rm = (const int*)d_in[2];
    f4* out = (f4*)d_out;

    const int block = 256;
    const int grid = N * BLOCKS_PER_SAMPLE;  // 25600 blocks, no loop
    MaskEncoding_39307540693367_kernel<<<grid, block, 0, stream>>>(in, apply_mask, rm, out);
}